// Round 1
// baseline (381.295 us; speedup 1.0000x reference)
//
#include <hip/hip_runtime.h>
#include <math.h>

#define BB 2
#define NN 2048
#define MM 4096
#define DD 256
#define HH 8
#define DK 32
#define KNN 16

// ---------- tiled f32 GEMM: out[r][c] = sum_k A[r][k]*W[k][c] + bias[c]
// A: [rows,256], W: [256,256] row-major (din x dout), 64x64 tile, 256 thr.
__global__ __launch_bounds__(256)
void gemm_bias_256(const float* __restrict__ A, const float* __restrict__ W,
                   const float* __restrict__ bias, float* __restrict__ out)
{
    __shared__ float As[16][64];
    __shared__ float Bs[16][64];
    const int tid = threadIdx.x;
    const int tx = tid & 15, ty = tid >> 4;
    const int row0 = blockIdx.x * 64, col0 = blockIdx.y * 64;
    float acc[4][4] = {};
    for (int k0 = 0; k0 < 256; k0 += 16) {
        #pragma unroll
        for (int j = 0; j < 4; ++j) {
            int idx = tid + j * 256;
            int i = idx >> 4, k = idx & 15;
            As[k][i] = A[(size_t)(row0 + i) * 256 + k0 + k];
        }
        #pragma unroll
        for (int j = 0; j < 4; ++j) {
            int idx = tid + j * 256;
            int kk = idx >> 6, c = idx & 63;
            Bs[kk][c] = W[(size_t)(k0 + kk) * 256 + col0 + c];
        }
        __syncthreads();
        #pragma unroll
        for (int k = 0; k < 16; ++k) {
            float4 av = *(const float4*)&As[k][ty * 4];
            float4 bv = *(const float4*)&Bs[k][tx * 4];
            float a[4] = {av.x, av.y, av.z, av.w};
            float b[4] = {bv.x, bv.y, bv.z, bv.w};
            #pragma unroll
            for (int u = 0; u < 4; ++u)
                #pragma unroll
                for (int v = 0; v < 4; ++v)
                    acc[u][v] = fmaf(a[u], b[v], acc[u][v]);
        }
        __syncthreads();
    }
    #pragma unroll
    for (int u = 0; u < 4; ++u) {
        int r = row0 + ty * 4 + u;
        #pragma unroll
        for (int v = 0; v < 4; ++v) {
            int c = col0 + tx * 4 + v;
            out[(size_t)r * 256 + c] = acc[u][v] + bias[c];
        }
    }
}

// ---------- kNN: per (b,n) find 16 smallest squared distances (f64 to match
// the f64 numpy reference's top-k set at boundaries).
__global__ __launch_bounds__(256)
void knn_kernel(const float* __restrict__ src, const float* __restrict__ tgt,
                int* __restrict__ knn_idx)
{
    __shared__ double dist[MM];
    __shared__ double rv[256];
    __shared__ int    ri[256];
    const int bn = blockIdx.x;          // b*N + n
    const int b  = bn >> 11;
    const int t  = threadIdx.x;
    const float* sp = src + (size_t)bn * 3;
    const double px = sp[0], py = sp[1], pz = sp[2];
    const double x2 = px * px + py * py + pz * pz;
    const float* tb = tgt + (size_t)b * MM * 3;
    for (int m = t; m < MM; m += 256) {
        double txx = tb[m * 3 + 0], tyy = tb[m * 3 + 1], tzz = tb[m * 3 + 2];
        double y2  = txx * txx + tyy * tyy + tzz * tzz;
        double dot = px * txx + py * tyy + pz * tzz;
        dist[m] = (x2 + y2) - 2.0 * dot;
    }
    __syncthreads();
    int* kout = knn_idx + (size_t)bn * KNN;
    for (int sel = 0; sel < KNN; ++sel) {
        double best = 1e300; int bi = MM;
        for (int m = t; m < MM; m += 256) {
            double v = dist[m];
            if (v < best) { best = v; bi = m; }
        }
        rv[t] = best; ri[t] = bi;
        __syncthreads();
        for (int s = 128; s > 0; s >>= 1) {
            if (t < s) {
                double ov = rv[t + s]; int oi = ri[t + s];
                if (ov < rv[t] || (ov == rv[t] && oi < ri[t])) { rv[t] = ov; ri[t] = oi; }
            }
            __syncthreads();
        }
        if (t == 0) {
            kout[sel] = ri[0];
            dist[ri[0]] = 1e300;
        }
        __syncthreads();
    }
}

// ---------- gathered 16-way attention + residual; scatter avg_attn
__global__ __launch_bounds__(256)
void attn_kernel(const float* __restrict__ Q, const float* __restrict__ Kb,
                 const float* __restrict__ Vb, const int* __restrict__ knn_idx,
                 const float* __restrict__ src_fea,
                 float* __restrict__ X, float* __restrict__ avg_attn)
{
    __shared__ float Kt[KNN][257];   // +1 pad: breaks same-bank column reads
    __shared__ float Vt[KNN][257];
    __shared__ float q[DD];
    __shared__ float sc[HH][KNN];
    __shared__ float pw[HH][KNN];
    __shared__ int   idx[KNN];
    const int bn = blockIdx.x;
    const int b  = bn >> 11;
    const int t  = threadIdx.x;
    if (t < KNN) idx[t] = knn_idx[(size_t)bn * KNN + t];
    q[t] = Q[(size_t)bn * DD + t];
    __syncthreads();
    #pragma unroll
    for (int r = 0; r < KNN; ++r) {
        size_t rowoff = ((size_t)b * MM + idx[r]) * DD;
        Kt[r][t] = Kb[rowoff + t];
        Vt[r][t] = Vb[rowoff + t];
    }
    __syncthreads();
    if (t < HH * KNN) {                 // 128 threads: one (h,k) dot each
        int h = t >> 4, k = t & 15;
        float s = 0.f;
        const float* qh = &q[h * DK];
        const float* kh = &Kt[k][h * DK];
        #pragma unroll
        for (int j = 0; j < DK; ++j) s = fmaf(qh[j], kh[j], s);
        sc[h][k] = s * 0.17677669529663688f;   // 32^-0.5
    }
    __syncthreads();
    if (t < HH) {                        // softmax over 16 per head
        float mx = -1e30f;
        #pragma unroll
        for (int k = 0; k < KNN; ++k) mx = fmaxf(mx, sc[t][k]);
        float e[KNN]; float sum = 0.f;
        #pragma unroll
        for (int k = 0; k < KNN; ++k) { e[k] = expf(sc[t][k] - mx); sum += e[k]; }
        float inv = 1.0f / sum;
        #pragma unroll
        for (int k = 0; k < KNN; ++k) pw[t][k] = e[k] * inv;
    }
    __syncthreads();
    if (t < KNN) {                       // avg over heads -> scatter
        float a = 0.f;
        #pragma unroll
        for (int h = 0; h < HH; ++h) a += pw[h][t];
        avg_attn[(size_t)bn * MM + idx[t]] = a * (1.0f / HH);
    }
    {                                    // out = P·V, + residual
        int h = t >> 5;
        float acc = 0.f;
        #pragma unroll
        for (int k = 0; k < KNN; ++k) acc = fmaf(pw[h][k], Vt[k][t], acc);
        X[(size_t)bn * DD + t] = acc + src_fea[(size_t)bn * DD + t];
    }
}

// ---------- LayerNorm + ReLU over rows of 256
__global__ __launch_bounds__(256)
void ln_relu_kernel(const float* __restrict__ in, const float* __restrict__ g,
                    const float* __restrict__ bb, float* __restrict__ out)
{
    __shared__ float red[256];
    const int row = blockIdx.x, t = threadIdx.x;
    float v = in[(size_t)row * 256 + t];
    red[t] = v; __syncthreads();
    for (int s = 128; s > 0; s >>= 1) { if (t < s) red[t] += red[t + s]; __syncthreads(); }
    float mu = red[0] * (1.0f / 256.0f);
    __syncthreads();
    float d = v - mu;
    red[t] = d * d; __syncthreads();
    for (int s = 128; s > 0; s >>= 1) { if (t < s) red[t] += red[t + s]; __syncthreads(); }
    float var = red[0] * (1.0f / 256.0f);
    float y = d * (1.0f / sqrtf(var + 1e-5f)) * g[t] + bb[t];
    out[(size_t)row * 256 + t] = fmaxf(y, 0.0f);
}

extern "C" void kernel_launch(void* const* d_in, const int* in_sizes, int n_in,
                              void* d_out, int out_size, void* d_ws, size_t ws_size,
                              hipStream_t stream) {
    const float* src     = (const float*)d_in[0];
    const float* tgt     = (const float*)d_in[1];
    const float* src_fea = (const float*)d_in[2];
    const float* tgt_fea = (const float*)d_in[3];
    const float* Wq  = (const float*)d_in[4];   const float* bq  = (const float*)d_in[5];
    const float* Wk  = (const float*)d_in[6];   const float* bk  = (const float*)d_in[7];
    const float* Wv  = (const float*)d_in[8];   const float* bv  = (const float*)d_in[9];
    const float* Wo1 = (const float*)d_in[10];  const float* bo1 = (const float*)d_in[11];
    const float* lng = (const float*)d_in[12];  const float* lnb = (const float*)d_in[13];
    const float* Wo2 = (const float*)d_in[14];  const float* bo2 = (const float*)d_in[15];
    (void)in_sizes; (void)n_in; (void)out_size; (void)ws_size;

    float* out     = (float*)d_out;
    float* updated = out;                                   // [B,N,D]
    float* avg     = out + (size_t)BB * NN * DD;            // [B,N,M]

    // workspace layout (f32): Q 4MB | K 8MB | V 8MB | idx 256KB | X 4MB ≈ 24.3MB
    float* Qb  = (float*)d_ws;
    float* Kb  = Qb + (size_t)BB * NN * DD;
    float* Vb  = Kb + (size_t)BB * MM * DD;
    int*   knn = (int*)(Vb + (size_t)BB * MM * DD);
    float* X   = (float*)(knn + (size_t)BB * NN * KNN);
    float* T1  = Qb;   // reuse: Q dead after attn
    float* Hb  = Kb;   // reuse: K dead after attn

    hipMemsetAsync(avg, 0, (size_t)BB * NN * MM * sizeof(float), stream);

    dim3 blk(256);
    gemm_bias_256<<<dim3(BB * NN / 64, 4), blk, 0, stream>>>(src_fea, Wq, bq, Qb);
    gemm_bias_256<<<dim3(BB * MM / 64, 4), blk, 0, stream>>>(tgt_fea, Wk, bk, Kb);
    gemm_bias_256<<<dim3(BB * MM / 64, 4), blk, 0, stream>>>(tgt_fea, Wv, bv, Vb);
    knn_kernel<<<BB * NN, blk, 0, stream>>>(src, tgt, knn);
    attn_kernel<<<BB * NN, blk, 0, stream>>>(Qb, Kb, Vb, knn, src_fea, X, avg);
    gemm_bias_256<<<dim3(BB * NN / 64, 4), blk, 0, stream>>>(X, Wo1, bo1, T1);
    ln_relu_kernel<<<BB * NN, blk, 0, stream>>>(T1, lng, lnb, Hb);
    gemm_bias_256<<<dim3(BB * NN / 64, 4), blk, 0, stream>>>(Hb, Wo2, bo2, updated);
}

// Round 3
// 232.449 us; speedup vs baseline: 1.6403x; 1.6403x over previous
//
#include <hip/hip_runtime.h>
#include <math.h>

#define BB 2
#define NN 2048
#define MM 4096
#define DD 256
#define HH 8
#define DK 32
#define KNN 16

typedef __attribute__((ext_vector_type(8))) short short8;
typedef __attribute__((ext_vector_type(4))) float f32x4;
typedef unsigned long long u64;
typedef unsigned short u16;

static __device__ __forceinline__ u16 f2bf(float f) {
    union { float f; unsigned u; } v; v.f = f;
    unsigned r = v.u + 0x7FFF + ((v.u >> 16) & 1);   // round-to-nearest-even
    return (u16)(r >> 16);
}

// ---------- f32 -> bf16 bulk convert (8 elems/thread)
__global__ __launch_bounds__(256)
void cvt_bf16(const float* __restrict__ in, u16* __restrict__ out, int n8)
{
    int i = blockIdx.x * 256 + threadIdx.x;
    if (i >= n8) return;
    float4 a = ((const float4*)in)[i * 2];
    float4 b = ((const float4*)in)[i * 2 + 1];
    short8 s;
    s[0] = (short)f2bf(a.x); s[1] = (short)f2bf(a.y);
    s[2] = (short)f2bf(a.z); s[3] = (short)f2bf(a.w);
    s[4] = (short)f2bf(b.x); s[5] = (short)f2bf(b.y);
    s[6] = (short)f2bf(b.z); s[7] = (short)f2bf(b.w);
    ((short8*)out)[i] = s;
}

// ---------- transpose + convert the five 256x256 weights: WT[c][k] = bf16(W[k][c])
__global__ __launch_bounds__(256)
void wtrans(const float* W0, const float* W1, const float* W2, const float* W3, const float* W4,
            u16* O0, u16* O1, u16* O2, u16* O3, u16* O4)
{
    __shared__ float tile[64][65];
    const int bid = blockIdx.x;               // 5 * 16 blocks
    const int m = bid >> 4, tl = bid & 15;
    const int tr = (tl >> 2) * 64, tc = (tl & 3) * 64;
    const float* W = m == 0 ? W0 : m == 1 ? W1 : m == 2 ? W2 : m == 3 ? W3 : W4;
    u16*        O = m == 0 ? O0 : m == 1 ? O1 : m == 2 ? O2 : m == 3 ? O3 : O4;
    const int c = threadIdx.x & 63, r4 = threadIdx.x >> 6;
    #pragma unroll
    for (int i = 0; i < 16; ++i) {
        const int r = (r4 << 4) + i;
        tile[r][c] = W[(size_t)(tr + r) * 256 + tc + c];
    }
    __syncthreads();
    #pragma unroll
    for (int i = 0; i < 16; ++i) {
        const int cc = (r4 << 4) + i;
        O[(size_t)(tc + cc) * 256 + tr + c] = f2bf(tile[c][cc]);
    }
}

// ---------- bf16 MFMA GEMM: out[r][c] = sum_k A[r][k]*W[k][c] + bias[c]
// A bf16 [rows][256], WT bf16 [256cols][256k] (pre-transposed), out f32.
// 64x64 tile, BK=64, 4 waves, XOR-swizzled LDS (byte ^= (row&7)<<4).
__global__ __launch_bounds__(256)
void gemm_bf16(const u16* __restrict__ A, const u16* __restrict__ WT,
               const float* __restrict__ bias, float* __restrict__ out)
{
    __shared__ u16 As[64 * 64];
    __shared__ u16 Bs[64 * 64];
    const int t = threadIdx.x;
    const int lane = t & 63;
    const int w = t >> 6;
    const size_t row0 = (size_t)blockIdx.x * 64;
    const int col0 = blockIdx.y * 64;
    const int wr = (w >> 1) * 32;
    const int wc = (w & 1) * 32;
    f32x4 acc[2][2] = {};
    for (int k0 = 0; k0 < 256; k0 += 64) {
        #pragma unroll
        for (int e = 0; e < 2; ++e) {
            const int flat = t + (e << 8);
            const int r = flat >> 3;
            const int kc = (flat & 7) << 3;
            const int off = ((r << 7) + (kc << 1)) ^ ((r & 7) << 4);
            *(short8*)((char*)As + off) = *(const short8*)(A + (row0 + r) * 256 + k0 + kc);
            *(short8*)((char*)Bs + off) = *(const short8*)(WT + (size_t)(col0 + r) * 256 + k0 + kc);
        }
        __syncthreads();
        #pragma unroll
        for (int kk = 0; kk < 64; kk += 32) {
            const int kb = (kk + ((lane >> 4) << 3)) << 1;
            short8 af[2], bfr[2];
            #pragma unroll
            for (int i = 0; i < 2; ++i) {
                const int ra = wr + (i << 4) + (lane & 15);
                af[i]  = *(const short8*)((const char*)As + (((ra << 7) + kb) ^ ((ra & 7) << 4)));
                const int rb = wc + (i << 4) + (lane & 15);
                bfr[i] = *(const short8*)((const char*)Bs + (((rb << 7) + kb) ^ ((rb & 7) << 4)));
            }
            #pragma unroll
            for (int mi = 0; mi < 2; ++mi)
                #pragma unroll
                for (int ni = 0; ni < 2; ++ni)
                    acc[mi][ni] = __builtin_amdgcn_mfma_f32_16x16x32_bf16(af[mi], bfr[ni], acc[mi][ni], 0, 0, 0);
        }
        __syncthreads();
    }
    const int cq = lane & 15;
    const int rq = (lane >> 4) << 2;
    #pragma unroll
    for (int ni = 0; ni < 2; ++ni) {
        const int col = col0 + wc + (ni << 4) + cq;
        const float bv = bias[col];
        #pragma unroll
        for (int mi = 0; mi < 2; ++mi) {
            const size_t rbase = (row0 + wr + (mi << 4) + rq) * 256 + col;
            #pragma unroll
            for (int e2 = 0; e2 < 4; ++e2)
                out[rbase + (size_t)e2 * 256] = acc[mi][ni][e2] + bv;
        }
    }
}

// ---------- kNN v2: one wave per query, candidates in registers as packed u64
// pk = (f64 dist bits & ~0xFFF) | index  -> order == (dist, index), np-tie-match.
__global__ __launch_bounds__(256)
void knn_kernel(const float* __restrict__ src, const float* __restrict__ tgt,
                int* __restrict__ knn_idx)
{
    const int t = threadIdx.x;
    const int lane = t & 63;
    const int bn = (blockIdx.x << 2) + (t >> 6);    // 4 queries / block
    const int b = bn >> 11;
    const float* sp = src + (size_t)bn * 3;
    const double px = sp[0], py = sp[1], pz = sp[2];
    const double x2 = px * px + py * py + pz * pz;
    const float* tb = tgt + (size_t)b * MM * 3;
    u64 pk[64];
    #pragma unroll
    for (int j = 0; j < 64; ++j) {
        const int m = (j << 6) + lane;
        const double tx = tb[m * 3 + 0], ty = tb[m * 3 + 1], tz = tb[m * 3 + 2];
        const double y2 = tx * tx + ty * ty + tz * tz;
        const double dt = px * tx + py * ty + pz * tz;
        double d = (x2 + y2) - 2.0 * dt;
        d = d > 0.0 ? d : 0.0;
        pk[j] = (((u64)__double_as_longlong(d)) & ~0xFFFULL) | (u64)m;
    }
    u64 last1 = 0;
    unsigned myidx = 0;
    for (int sel = 0; sel < 16; ++sel) {
        u64 b0 = ~0ULL, b1 = ~0ULL, b2 = ~0ULL, b3 = ~0ULL;
        #pragma unroll
        for (int j = 0; j < 64; j += 4) {           // 4 independent min chains (ILP)
            u64 u0 = pk[j + 0] - last1; b0 = u0 < b0 ? u0 : b0;
            u64 u1 = pk[j + 1] - last1; b1 = u1 < b1 ? u1 : b1;
            u64 u2 = pk[j + 2] - last1; b2 = u2 < b2 ? u2 : b2;
            u64 u3 = pk[j + 3] - last1; b3 = u3 < b3 ? u3 : b3;
        }
        u64 best = b0 < b1 ? b0 : b1;
        u64 bst2 = b2 < b3 ? b2 : b3;
        best = best < bst2 ? best : bst2;
        #pragma unroll
        for (int s = 32; s; s >>= 1) {
            u64 o = __shfl_xor(best, s, 64);
            best = o < best ? o : best;
        }
        const u64 winner = best + last1;
        if (lane == sel) myidx = (unsigned)(winner & 0xFFF);
        last1 = winner + 1;
    }
    if (lane < 16) knn_idx[(size_t)bn * KNN + lane] = (int)myidx;
}

// ---------- gathered 16-way attention + residual; scatter avg_attn; X out bf16
__global__ __launch_bounds__(256)
void attn_kernel(const float* __restrict__ Q, const float* __restrict__ Kb,
                 const float* __restrict__ Vb, const int* __restrict__ knn_idx,
                 const float* __restrict__ src_fea,
                 u16* __restrict__ Xb, float* __restrict__ avg_attn)
{
    __shared__ float Kt[KNN][257];
    __shared__ float Vt[KNN][257];
    __shared__ float q[DD];
    __shared__ float sc[HH][KNN];
    __shared__ float pw[HH][KNN];
    __shared__ int   idx[KNN];
    const int bn = blockIdx.x;
    const int b  = bn >> 11;
    const int t  = threadIdx.x;
    if (t < KNN) idx[t] = knn_idx[(size_t)bn * KNN + t];
    q[t] = Q[(size_t)bn * DD + t];
    __syncthreads();
    #pragma unroll
    for (int r = 0; r < KNN; ++r) {
        size_t rowoff = ((size_t)b * MM + idx[r]) * DD;
        Kt[r][t] = Kb[rowoff + t];
        Vt[r][t] = Vb[rowoff + t];
    }
    __syncthreads();
    if (t < HH * KNN) {
        int h = t >> 4, k = t & 15;
        float s = 0.f;
        const float* qh = &q[h * DK];
        const float* kh = &Kt[k][h * DK];
        #pragma unroll
        for (int j = 0; j < DK; ++j) s = fmaf(qh[j], kh[j], s);
        sc[h][k] = s * 0.17677669529663688f;
    }
    __syncthreads();
    if (t < HH) {
        float mx = -1e30f;
        #pragma unroll
        for (int k = 0; k < KNN; ++k) mx = fmaxf(mx, sc[t][k]);
        float e[KNN]; float sum = 0.f;
        #pragma unroll
        for (int k = 0; k < KNN; ++k) { e[k] = expf(sc[t][k] - mx); sum += e[k]; }
        float inv = 1.0f / sum;
        #pragma unroll
        for (int k = 0; k < KNN; ++k) pw[t][k] = e[k] * inv;
    }
    __syncthreads();
    if (t < KNN) {
        float a = 0.f;
        #pragma unroll
        for (int h = 0; h < HH; ++h) a += pw[h][t];
        avg_attn[(size_t)bn * MM + idx[t]] = a * (1.0f / HH);
    }
    {
        int h = t >> 5;
        float acc = 0.f;
        #pragma unroll
        for (int k = 0; k < KNN; ++k) acc = fmaf(pw[h][k], Vt[k][t], acc);
        Xb[(size_t)bn * DD + t] = f2bf(acc + src_fea[(size_t)bn * DD + t]);
    }
}

// ---------- LayerNorm + ReLU over rows of 256; out bf16
__global__ __launch_bounds__(256)
void ln_relu_kernel(const float* __restrict__ in, const float* __restrict__ g,
                    const float* __restrict__ bb, u16* __restrict__ out)
{
    __shared__ float red[256];
    const int row = blockIdx.x, t = threadIdx.x;
    float v = in[(size_t)row * 256 + t];
    red[t] = v; __syncthreads();
    for (int s = 128; s > 0; s >>= 1) { if (t < s) red[t] += red[t + s]; __syncthreads(); }
    float mu = red[0] * (1.0f / 256.0f);
    __syncthreads();
    float d = v - mu;
    red[t] = d * d; __syncthreads();
    for (int s = 128; s > 0; s >>= 1) { if (t < s) red[t] += red[t + s]; __syncthreads(); }
    float var = red[0] * (1.0f / 256.0f);
    float y = d * (1.0f / sqrtf(var + 1e-5f)) * g[t] + bb[t];
    out[(size_t)row * 256 + t] = f2bf(fmaxf(y, 0.0f));
}

extern "C" void kernel_launch(void* const* d_in, const int* in_sizes, int n_in,
                              void* d_out, int out_size, void* d_ws, size_t ws_size,
                              hipStream_t stream) {
    const float* src     = (const float*)d_in[0];
    const float* tgt     = (const float*)d_in[1];
    const float* src_fea = (const float*)d_in[2];
    const float* tgt_fea = (const float*)d_in[3];
    const float* Wq  = (const float*)d_in[4];   const float* bq  = (const float*)d_in[5];
    const float* Wk  = (const float*)d_in[6];   const float* bk  = (const float*)d_in[7];
    const float* Wv  = (const float*)d_in[8];   const float* bv  = (const float*)d_in[9];
    const float* Wo1 = (const float*)d_in[10];  const float* bo1 = (const float*)d_in[11];
    const float* lng = (const float*)d_in[12];  const float* lnb = (const float*)d_in[13];
    const float* Wo2 = (const float*)d_in[14];  const float* bo2 = (const float*)d_in[15];
    (void)in_sizes; (void)n_in; (void)out_size; (void)ws_size;

    float* out     = (float*)d_out;
    float* updated = out;                                   // [B,N,D] f32
    float* avg     = out + (size_t)BB * NN * DD;            // [B,N,M] f32

    // workspace layout
    char* p = (char*)d_ws;
    u16* tfb = (u16*)p;  p += (size_t)BB * MM * DD * 2;     // tgt_fea bf16   4MB
    u16* sfb = (u16*)p;  p += (size_t)BB * NN * DD * 2;     // src_fea bf16   2MB
    u16* WTq = (u16*)p;  p += 256 * 256 * 2;
    u16* WTk = (u16*)p;  p += 256 * 256 * 2;
    u16* WTv = (u16*)p;  p += 256 * 256 * 2;
    u16* WTo1= (u16*)p;  p += 256 * 256 * 2;
    u16* WTo2= (u16*)p;  p += 256 * 256 * 2;
    float* Qb = (float*)p; p += (size_t)BB * NN * DD * 4;   // 4MB
    float* Kb = (float*)p; p += (size_t)BB * MM * DD * 4;   // 8MB
    float* Vb = (float*)p; p += (size_t)BB * MM * DD * 4;   // 8MB
    int*  knn = (int*)p;   p += (size_t)BB * NN * KNN * 4;  // 256KB
    u16*  Xbf = (u16*)p;   p += (size_t)BB * NN * DD * 2;   // 2MB
    float* T1 = (float*)p; p += (size_t)BB * NN * DD * 4;   // 4MB
    u16*  Hbf = (u16*)p;   p += (size_t)BB * NN * DD * 2;   // 2MB

    hipMemsetAsync(avg, 0, (size_t)BB * NN * MM * sizeof(float), stream);

    dim3 blk(256);
    knn_kernel<<<BB * NN / 4, blk, 0, stream>>>(src, tgt, knn);
    cvt_bf16<<<(BB * MM * DD / 8 + 255) / 256, blk, 0, stream>>>(tgt_fea, tfb, BB * MM * DD / 8);
    cvt_bf16<<<(BB * NN * DD / 8 + 255) / 256, blk, 0, stream>>>(src_fea, sfb, BB * NN * DD / 8);
    wtrans<<<80, blk, 0, stream>>>(Wq, Wk, Wv, Wo1, Wo2, WTq, WTk, WTv, WTo1, WTo2);
    gemm_bf16<<<dim3(BB * NN / 64, 4), blk, 0, stream>>>(sfb, WTq, bq, Qb);
    gemm_bf16<<<dim3(BB * MM / 64, 4), blk, 0, stream>>>(tfb, WTk, bk, Kb);
    gemm_bf16<<<dim3(BB * MM / 64, 4), blk, 0, stream>>>(tfb, WTv, bv, Vb);
    attn_kernel<<<BB * NN, blk, 0, stream>>>(Qb, Kb, Vb, knn, src_fea, Xbf, avg);
    gemm_bf16<<<dim3(BB * NN / 64, 4), blk, 0, stream>>>(Xbf, WTo1, bo1, T1);
    ln_relu_kernel<<<BB * NN, blk, 0, stream>>>(T1, lng, lnb, Hbf);
    gemm_bf16<<<dim3(BB * NN / 64, 4), blk, 0, stream>>>(Hbf, WTo2, bo2, updated);
}